// Round 5
// baseline (345.810 us; speedup 1.0000x reference)
//
#include <hip/hip_runtime.h>
#include <hip/hip_bf16.h>

#define N_NODES 50000
#define N_EDGES 800000
#define IN_DIM  128
#define H_DIM   96
#define C_DIM   10
#define L_LAYERS 4
#define K_EIG   16
#define LN_EPS_F 1e-5f

typedef __attribute__((ext_vector_type(8))) short bf16x8;
typedef __attribute__((ext_vector_type(4))) float f32x4;

// ---------- device helpers ----------

__device__ __forceinline__ float gelu_f(float x) {
    return 0.5f * x * (1.0f + erff(x * 0.7071067811865476f));
}

__device__ __forceinline__ ushort f2bf(float f) {
    union { float f; unsigned int u; } v; v.f = f;
    unsigned int r = v.u + 0x7fffu + ((v.u >> 16) & 1u);
    return (ushort)(r >> 16);
}

__device__ __forceinline__ float bflo(unsigned int v) { return __uint_as_float(v << 16); }
__device__ __forceinline__ float bfhi(unsigned int v) { return __uint_as_float(v & 0xffff0000u); }

// ---------- graph preprocessing ----------

__global__ void k_count(const int* __restrict__ dst, int* __restrict__ cnt) {
    int e = blockIdx.x * 256 + threadIdx.x;
    if (e < N_EDGES) atomicAdd(&cnt[dst[e]], 1);
}

__global__ void k_scanA(const int* __restrict__ cnt, int* __restrict__ rowst,
                        int* __restrict__ btot, float* __restrict__ dinv, int n) {
    __shared__ int wsum[16];
    const int tid = threadIdx.x, lane = tid & 63, wid = tid >> 6;
    int i = blockIdx.x * 1024 + tid;
    int v = (i < n) ? cnt[i] : 0;
    if (i < n) dinv[i] = rsqrtf((float)v + 1.0f);
    int s = v;
#pragma unroll
    for (int off = 1; off < 64; off <<= 1) {
        int t = __shfl_up(s, off);
        if (lane >= off) s += t;
    }
    if (lane == 63) wsum[wid] = s;
    __syncthreads();
    if (tid < 64) {
        int ws = (lane < 16) ? wsum[lane] : 0;
#pragma unroll
        for (int off = 1; off < 16; off <<= 1) {
            int t = __shfl_up(ws, off);
            if (lane >= off) ws += t;
        }
        if (lane < 16) wsum[lane] = ws;
    }
    __syncthreads();
    int woff = (wid > 0) ? wsum[wid - 1] : 0;
    if (i < n) rowst[i] = woff + s - v;
    if (tid == 0) btot[blockIdx.x] = wsum[15];
}

__global__ void k_scanB(int* __restrict__ btot, int* __restrict__ bpre,
                        int* __restrict__ rowst, int n, int nblk) {
    int lane = threadIdx.x;
    int v = (lane < nblk) ? btot[lane] : 0;
    int s = v;
#pragma unroll
    for (int off = 1; off < 64; off <<= 1) {
        int t = __shfl_up(s, off);
        if (lane >= off) s += t;
    }
    if (lane < nblk) bpre[lane] = s - v;
    if (lane == 63) rowst[n] = s;
}

__global__ void k_scanC(int* __restrict__ rowst, const int* __restrict__ bpre, int n) {
    int i = blockIdx.x * 1024 + threadIdx.x;
    if (i < n) rowst[i] += bpre[blockIdx.x];
}

__global__ void k_fill(const int* __restrict__ src, const int* __restrict__ dst,
                       const float* __restrict__ dinv, const int* __restrict__ rowst,
                       int* __restrict__ cursor, int2* __restrict__ csr) {
    int e = blockIdx.x * 256 + threadIdx.x;
    if (e >= N_EDGES) return;
    int s = src[e], d = dst[e];
    int p = atomicAdd(&cursor[d], 1);
    csr[rowst[d] + p] = make_int2(s, __float_as_int(dinv[s] * dinv[d]));
}

// ---------- weight prep: transpose + bf16 ----------
// layout: [0,12288): enc_W ([n][k], K=128); then 8 mats of 9216 (K=96):
// phi_w2, rho_w1, rho_w2, conv0..3, head_w1

struct WSrc { const float* p[9]; };

__global__ void k_prep(WSrc ws, ushort* __restrict__ out) {
    int idx = blockIdx.x * 256 + threadIdx.x;
    if (idx < 12288) {
        int n = idx >> 7, k = idx & 127;
        out[idx] = f2bf(ws.p[0][k * 96 + n]);
    } else if (idx < 12288 + 8 * 9216) {
        int j = idx - 12288;
        int m = j / 9216, r = j - m * 9216;
        int n = r / 96, k = r - n * 96;
        out[idx] = f2bf(ws.p[m + 1][k * 96 + n]);
    }
}

// ---------- MFMA GEMM, wave-per-16-rows, all operands via registers ----------
// N_NODES = 3125 * 16 exactly -> no row bounds checks.
// EPI 0: -> bf16 out
// EPI 2: LN(.+bias; g,beta) -> f32
// EPI 5: head: t = LN(gelu(.+bias); g,beta); out = t @ W2 + b2  (96 -> 10, f32)

template <int K_DIM, typename XT, int EPI>
__launch_bounds__(256)
__global__ void k_gemm(const XT* __restrict__ X, const ushort* __restrict__ Wt,
                       const float* __restrict__ bias, const float* __restrict__ g,
                       const float* __restrict__ beta,
                       const float* __restrict__ W2, const float* __restrict__ b2,
                       void* __restrict__ outv) {
    constexpr int NK = K_DIM / 32;
    __shared__ float W2l[(EPI == 5) ? 96 * 11 : 1];
    if constexpr (EPI == 5) {
        for (int i = threadIdx.x; i < 960; i += 256) {
            int n = i / 10, c = i - n * 10;
            W2l[n * 11 + c] = W2[i];
        }
        __syncthreads();
    }
    const int lane = threadIdx.x & 63, wv = threadIdx.x >> 6;
    const int lrow = lane & 15, lk = (lane >> 4) * 8;
    const int grp = blockIdx.x * 4 + wv;
    if (grp >= N_NODES / 16) return;

    // W fragments in registers (18 or 24 x bf16x8), L2-broadcast across waves
    bf16x8 wf[6][NK];
#pragma unroll
    for (int nn = 0; nn < 6; ++nn)
#pragma unroll
        for (int kk = 0; kk < NK; ++kk)
            wf[nn][kk] = *(const bf16x8*)(&Wt[(size_t)(nn * 16 + lrow) * K_DIM + kk * 32 + lk]);

    // A fragments straight from global (k-contiguous 16B per lane)
    bf16x8 af[NK];
    const int arow = grp * 16 + lrow;
    if constexpr (sizeof(XT) == 4) {
#pragma unroll
        for (int kk = 0; kk < NK; ++kk) {
            const float4* p = (const float4*)((const float*)X + (size_t)arow * K_DIM + kk * 32 + lk);
            float4 a = p[0], b = p[1];
            union { bf16x8 v; unsigned u[4]; } pk;
            pk.u[0] = (unsigned)f2bf(a.x) | ((unsigned)f2bf(a.y) << 16);
            pk.u[1] = (unsigned)f2bf(a.z) | ((unsigned)f2bf(a.w) << 16);
            pk.u[2] = (unsigned)f2bf(b.x) | ((unsigned)f2bf(b.y) << 16);
            pk.u[3] = (unsigned)f2bf(b.z) | ((unsigned)f2bf(b.w) << 16);
            af[kk] = pk.v;
        }
    } else {
#pragma unroll
        for (int kk = 0; kk < NK; ++kk)
            af[kk] = *(const bf16x8*)((const ushort*)X + (size_t)arow * K_DIM + kk * 32 + lk);
    }

    f32x4 acc[6];
#pragma unroll
    for (int nn = 0; nn < 6; ++nn) { acc[nn][0] = 0.f; acc[nn][1] = 0.f; acc[nn][2] = 0.f; acc[nn][3] = 0.f; }
#pragma unroll
    for (int nn = 0; nn < 6; ++nn)
#pragma unroll
        for (int kk = 0; kk < NK; ++kk)
            acc[nn] = __builtin_amdgcn_mfma_f32_16x16x32_bf16(af[kk], wf[nn][kk], acc[nn], 0, 0, 0);

    float bcol[6], gcol[6], ncol[6];
    if (EPI == 2 || EPI == 5) {
#pragma unroll
        for (int nn = 0; nn < 6; ++nn) {
            bcol[nn] = bias[nn * 16 + lrow];
            gcol[nn] = g[nn * 16 + lrow];
            ncol[nn] = beta[nn * 16 + lrow];
        }
    }

    const int rbase = grp * 16 + (lane >> 4) * 4;
#pragma unroll
    for (int reg = 0; reg < 4; ++reg) {
        const int row = rbase + reg;
        float v[6];
#pragma unroll
        for (int nn = 0; nn < 6; ++nn) {
            v[nn] = acc[nn][reg];
            if (EPI == 2 || EPI == 5) v[nn] += bcol[nn];
            if (EPI == 5) v[nn] = gelu_f(v[nn]);
        }
        if (EPI == 2 || EPI == 5) {
            float s = 0.f, s2 = 0.f;
#pragma unroll
            for (int nn = 0; nn < 6; ++nn) { s += v[nn]; s2 += v[nn] * v[nn]; }
#pragma unroll
            for (int off = 1; off < 16; off <<= 1) { s += __shfl_xor(s, off); s2 += __shfl_xor(s2, off); }
            float mean = s * (1.f / 96.f);
            float var = s2 * (1.f / 96.f) - mean * mean;
            float rs = rsqrtf(var + LN_EPS_F);
#pragma unroll
            for (int nn = 0; nn < 6; ++nn) v[nn] = (v[nn] - mean) * rs * gcol[nn] + ncol[nn];
        }
        if constexpr (EPI == 5) {
            float pc[C_DIM];
#pragma unroll
            for (int c = 0; c < C_DIM; ++c) pc[c] = 0.f;
#pragma unroll
            for (int nn = 0; nn < 6; ++nn) {
                const float* wr = &W2l[(nn * 16 + lrow) * 11];
#pragma unroll
                for (int c = 0; c < C_DIM; ++c) pc[c] = fmaf(v[nn], wr[c], pc[c]);
            }
#pragma unroll
            for (int off = 1; off < 16; off <<= 1) {
#pragma unroll
                for (int c = 0; c < C_DIM; ++c) pc[c] += __shfl_xor(pc[c], off);
            }
            if (lrow == 0) {
#pragma unroll
                for (int c = 0; c < C_DIM; ++c)
                    ((float*)outv)[(size_t)row * C_DIM + c] = pc[c] + b2[c];
            }
        } else {
#pragma unroll
            for (int nn = 0; nn < 6; ++nn) {
                size_t idx = (size_t)row * 96 + nn * 16 + lrow;
                if (EPI == 0) ((ushort*)outv)[idx] = f2bf(v[nn]);
                else ((float*)outv)[idx] = v[nn];
            }
        }
    }
}

// ---------- fused PE: h += rho2(relu(rho1(phi2(sum_k relu(z@phi_w1))))) ----------

__launch_bounds__(256)
__global__ void k_pe(const float* __restrict__ eigvecs, const float* __restrict__ eigvals,
                     const float* __restrict__ pe_eps, const float* __restrict__ phi_w1,
                     const ushort* __restrict__ w_phi2, const ushort* __restrict__ w_rho1,
                     const ushort* __restrict__ w_rho2, const float* __restrict__ rho_b1,
                     const float* __restrict__ rho_b2, float* __restrict__ h,
                     ushort* __restrict__ hb) {
    constexpr int KP = 104;
    __shared__ ushort WL[96 * KP];
    __shared__ ushort T[64 * KP];
    const int t = threadIdx.x;
    const int base = blockIdx.x * 64;

    for (int i = t; i < 96 * 12; i += 256) {
        int n = i / 12, kc = (i - n * 12) * 8;
        *(uint4*)(&WL[n * KP + kc]) = *(const uint4*)(&w_phi2[n * 96 + kc]);
    }
    {
        int r = t >> 2, jg = t & 3;
        int row = base + r;
        float s[24];
#pragma unroll
        for (int j = 0; j < 24; ++j) s[j] = 0.f;
        if (row < N_NODES) {
            float w0[24], w1v[24];
#pragma unroll
            for (int j = 0; j < 24; ++j) { w0[j] = phi_w1[jg * 24 + j]; w1v[j] = phi_w1[96 + jg * 24 + j]; }
            for (int k = 0; k < K_EIG; ++k) {
                float a = eigvecs[(size_t)row * K_EIG + k];
                float b = eigvals[(size_t)row * K_EIG + k] + pe_eps[k];
#pragma unroll
                for (int j = 0; j < 24; ++j) s[j] += fmaxf(fmaf(a, w0[j], b * w1v[j]), 0.f);
            }
        }
#pragma unroll
        for (int j = 0; j < 12; ++j) {
            unsigned pk = (unsigned)f2bf(s[2 * j]) | ((unsigned)f2bf(s[2 * j + 1]) << 16);
            *(unsigned*)(&T[r * KP + jg * 24 + 2 * j]) = pk;
        }
    }
    __syncthreads();

    const int lane = t & 63, w = t >> 6;
    const int lrow = lane & 15, lk = (lane >> 4) * 8;
    const int rsub = (lane >> 4) * 4;
    float bc2[6], bc3[6];
#pragma unroll
    for (int nn = 0; nn < 6; ++nn) { bc2[nn] = rho_b1[nn * 16 + lrow]; bc3[nn] = rho_b2[nn * 16 + lrow]; }

    f32x4 acc[6];

    // stage 1: T @ phi_w2 -> T
    {
        bf16x8 af[3];
#pragma unroll
        for (int kk = 0; kk < 3; ++kk) af[kk] = *(const bf16x8*)(&T[(w * 16 + lrow) * KP + kk * 32 + lk]);
#pragma unroll
        for (int nn = 0; nn < 6; ++nn) { acc[nn][0] = 0.f; acc[nn][1] = 0.f; acc[nn][2] = 0.f; acc[nn][3] = 0.f; }
#pragma unroll
        for (int nn = 0; nn < 6; ++nn)
#pragma unroll
            for (int kk = 0; kk < 3; ++kk)
                acc[nn] = __builtin_amdgcn_mfma_f32_16x16x32_bf16(
                    af[kk], *(const bf16x8*)(&WL[(nn * 16 + lrow) * KP + kk * 32 + lk]), acc[nn], 0, 0, 0);
        __syncthreads();
#pragma unroll
        for (int reg = 0; reg < 4; ++reg)
#pragma unroll
            for (int nn = 0; nn < 6; ++nn)
                T[(w * 16 + rsub + reg) * KP + nn * 16 + lrow] = f2bf(acc[nn][reg]);
        for (int i = t; i < 96 * 12; i += 256) {
            int n = i / 12, kc = (i - n * 12) * 8;
            *(uint4*)(&WL[n * KP + kc]) = *(const uint4*)(&w_rho1[n * 96 + kc]);
        }
        __syncthreads();
    }

    // stage 2: relu(T @ rho_w1 + b1) -> T
    {
        bf16x8 af[3];
#pragma unroll
        for (int kk = 0; kk < 3; ++kk) af[kk] = *(const bf16x8*)(&T[(w * 16 + lrow) * KP + kk * 32 + lk]);
#pragma unroll
        for (int nn = 0; nn < 6; ++nn) { acc[nn][0] = 0.f; acc[nn][1] = 0.f; acc[nn][2] = 0.f; acc[nn][3] = 0.f; }
#pragma unroll
        for (int nn = 0; nn < 6; ++nn)
#pragma unroll
            for (int kk = 0; kk < 3; ++kk)
                acc[nn] = __builtin_amdgcn_mfma_f32_16x16x32_bf16(
                    af[kk], *(const bf16x8*)(&WL[(nn * 16 + lrow) * KP + kk * 32 + lk]), acc[nn], 0, 0, 0);
        __syncthreads();
#pragma unroll
        for (int reg = 0; reg < 4; ++reg)
#pragma unroll
            for (int nn = 0; nn < 6; ++nn)
                T[(w * 16 + rsub + reg) * KP + nn * 16 + lrow] = f2bf(fmaxf(acc[nn][reg] + bc2[nn], 0.f));
        for (int i = t; i < 96 * 12; i += 256) {
            int n = i / 12, kc = (i - n * 12) * 8;
            *(uint4*)(&WL[n * KP + kc]) = *(const uint4*)(&w_rho2[n * 96 + kc]);
        }
        __syncthreads();
    }

    // stage 3: h += T @ rho_w2 + b2 ; hb = bf16(h)
    {
        bf16x8 af[3];
#pragma unroll
        for (int kk = 0; kk < 3; ++kk) af[kk] = *(const bf16x8*)(&T[(w * 16 + lrow) * KP + kk * 32 + lk]);
#pragma unroll
        for (int nn = 0; nn < 6; ++nn) { acc[nn][0] = 0.f; acc[nn][1] = 0.f; acc[nn][2] = 0.f; acc[nn][3] = 0.f; }
#pragma unroll
        for (int nn = 0; nn < 6; ++nn)
#pragma unroll
            for (int kk = 0; kk < 3; ++kk)
                acc[nn] = __builtin_amdgcn_mfma_f32_16x16x32_bf16(
                    af[kk], *(const bf16x8*)(&WL[(nn * 16 + lrow) * KP + kk * 32 + lk]), acc[nn], 0, 0, 0);
#pragma unroll
        for (int reg = 0; reg < 4; ++reg) {
            int row = base + w * 16 + rsub + reg;
            if (row < N_NODES) {
#pragma unroll
                for (int nn = 0; nn < 6; ++nn) {
                    size_t idx = (size_t)row * 96 + nn * 16 + lrow;
                    float hv = h[idx] + acc[nn][reg] + bc3[nn];
                    h[idx] = hv;
                    hb[idx] = f2bf(hv);
                }
            }
        }
    }
}

// ---------- GCN aggregation: 4 edge-groups x 16 feature-lanes ----------

__launch_bounds__(256)
__global__ void k_agg(const unsigned int* __restrict__ xw, const int* __restrict__ rowst,
                      const int2* __restrict__ csr, const float* __restrict__ dinv,
                      const float* __restrict__ bias, const float* __restrict__ g,
                      const float* __restrict__ beta, float* __restrict__ h,
                      ushort* __restrict__ hb) {
    const int lane = threadIdx.x & 63, wid = threadIdx.x >> 6;
    const int f = lane & 15;
    const int eg = lane >> 4;
    float bb[6], gg[6], be[6];
#pragma unroll
    for (int j = 0; j < 6; ++j) { bb[j] = bias[f * 6 + j]; gg[j] = g[f * 6 + j]; be[j] = beta[f * 6 + j]; }
    int w = blockIdx.x * 4 + wid, stride = gridDim.x * 4;
    for (int row = w; row < N_NODES; row += stride) {
        int rs = rowst[row], re = rowst[row + 1];
        float dv = dinv[row], d2 = dv * dv;
        float a[6];
        if (eg == 0) {
            uint3 v = *(const uint3*)(&xw[row * 48 + f * 3]);
            a[0] = bflo(v.x) * d2; a[1] = bfhi(v.x) * d2;
            a[2] = bflo(v.y) * d2; a[3] = bfhi(v.y) * d2;
            a[4] = bflo(v.z) * d2; a[5] = bfhi(v.z) * d2;
        } else {
#pragma unroll
            for (int j = 0; j < 6; ++j) a[j] = 0.f;
        }
        int i = rs + eg;
        for (; i + 4 < re; i += 8) {
            int2 e0 = csr[i], e1 = csr[i + 4];
            uint3 v0 = *(const uint3*)(&xw[e0.x * 48 + f * 3]);
            uint3 v1 = *(const uint3*)(&xw[e1.x * 48 + f * 3]);
            float w0 = __int_as_float(e0.y), w1 = __int_as_float(e1.y);
            a[0] = fmaf(w0, bflo(v0.x), a[0]); a[1] = fmaf(w0, bfhi(v0.x), a[1]);
            a[2] = fmaf(w0, bflo(v0.y), a[2]); a[3] = fmaf(w0, bfhi(v0.y), a[3]);
            a[4] = fmaf(w0, bflo(v0.z), a[4]); a[5] = fmaf(w0, bfhi(v0.z), a[5]);
            a[0] = fmaf(w1, bflo(v1.x), a[0]); a[1] = fmaf(w1, bfhi(v1.x), a[1]);
            a[2] = fmaf(w1, bflo(v1.y), a[2]); a[3] = fmaf(w1, bfhi(v1.y), a[3]);
            a[4] = fmaf(w1, bflo(v1.z), a[4]); a[5] = fmaf(w1, bfhi(v1.z), a[5]);
        }
        if (i < re) {
            int2 e0 = csr[i];
            uint3 v0 = *(const uint3*)(&xw[e0.x * 48 + f * 3]);
            float w0 = __int_as_float(e0.y);
            a[0] = fmaf(w0, bflo(v0.x), a[0]); a[1] = fmaf(w0, bfhi(v0.x), a[1]);
            a[2] = fmaf(w0, bflo(v0.y), a[2]); a[3] = fmaf(w0, bfhi(v0.y), a[3]);
            a[4] = fmaf(w0, bflo(v0.z), a[4]); a[5] = fmaf(w0, bfhi(v0.z), a[5]);
        }
#pragma unroll
        for (int j = 0; j < 6; ++j) {
            a[j] += __shfl_xor(a[j], 16);
            a[j] += __shfl_xor(a[j], 32);
        }
        float s = 0.f, s2 = 0.f;
#pragma unroll
        for (int j = 0; j < 6; ++j) {
            a[j] += bb[j];
            a[j] = gelu_f(a[j]);
            s += a[j]; s2 += a[j] * a[j];
        }
#pragma unroll
        for (int off = 1; off < 16; off <<= 1) { s += __shfl_xor(s, off); s2 += __shfl_xor(s2, off); }
        float mean = s * (1.f / 96.f);
        float var = s2 * (1.f / 96.f) - mean * mean;
        float rs_ = rsqrtf(var + LN_EPS_F);
        if (lane < 16) {
            float2* hp = (float2*)(h + (size_t)row * 96 + f * 6);
            float2 h0 = hp[0], h1 = hp[1], h2 = hp[2];
            float v0 = h0.x + (a[0] - mean) * rs_ * gg[0] + be[0];
            float v1 = h0.y + (a[1] - mean) * rs_ * gg[1] + be[1];
            float v2 = h1.x + (a[2] - mean) * rs_ * gg[2] + be[2];
            float v3 = h1.y + (a[3] - mean) * rs_ * gg[3] + be[3];
            float v4 = h2.x + (a[4] - mean) * rs_ * gg[4] + be[4];
            float v5 = h2.y + (a[5] - mean) * rs_ * gg[5] + be[5];
            hp[0] = make_float2(v0, v1); hp[1] = make_float2(v2, v3); hp[2] = make_float2(v4, v5);
            unsigned int* hbp = (unsigned int*)(hb + (size_t)row * 96 + f * 6);
            hbp[0] = (unsigned)f2bf(v0) | ((unsigned)f2bf(v1) << 16);
            hbp[1] = (unsigned)f2bf(v2) | ((unsigned)f2bf(v3) << 16);
            hbp[2] = (unsigned)f2bf(v4) | ((unsigned)f2bf(v5) << 16);
        }
    }
}

// ---------- host ----------

extern "C" void kernel_launch(void* const* d_in, const int* in_sizes, int n_in,
                              void* d_out, int out_size, void* d_ws, size_t ws_size,
                              hipStream_t stream) {
    (void)in_sizes; (void)n_in; (void)out_size; (void)ws_size;
    const float* x       = (const float*)d_in[0];
    const int*   eidx    = (const int*)d_in[1];
    const float* eigvecs = (const float*)d_in[2];
    const float* eigvals = (const float*)d_in[3];
    const float* enc_W   = (const float*)d_in[4];
    const float* enc_b   = (const float*)d_in[5];
    const float* in_g    = (const float*)d_in[6];
    const float* in_b    = (const float*)d_in[7];
    const float* phi_w1  = (const float*)d_in[8];
    const float* phi_w2  = (const float*)d_in[9];
    const float* rho_w1  = (const float*)d_in[10];
    const float* rho_b1  = (const float*)d_in[11];
    const float* rho_w2  = (const float*)d_in[12];
    const float* rho_b2  = (const float*)d_in[13];
    const float* pe_eps  = (const float*)d_in[14];
    const float* conv_W  = (const float*)d_in[15];
    const float* conv_b  = (const float*)d_in[16];
    const float* norm_g  = (const float*)d_in[17];
    const float* norm_b  = (const float*)d_in[18];
    const float* head_w1 = (const float*)d_in[19];
    const float* head_b1 = (const float*)d_in[20];
    const float* head_g  = (const float*)d_in[21];
    const float* head_b  = (const float*)d_in[22];
    const float* head_w2 = (const float*)d_in[23];
    const float* head_b2 = (const float*)d_in[24];
    float* out = (float*)d_out;

    const int* src = eidx;
    const int* dst = eidx + N_EDGES;

    char* ws = (char*)d_ws;
    size_t off = 0;
    auto alloc = [&](size_t bytes) {
        void* p = ws + off;
        off += (bytes + 255) & ~(size_t)255;
        return p;
    };
    float*  h      = (float*)alloc(sizeof(float) * (size_t)N_NODES * H_DIM);
    ushort* hb     = (ushort*)alloc(sizeof(ushort) * (size_t)N_NODES * H_DIM);
    ushort* bufA   = (ushort*)alloc(sizeof(ushort) * (size_t)N_NODES * H_DIM);
    ushort* wbf    = (ushort*)alloc(sizeof(ushort) * (12288 + 8 * 9216));
    int*    cnt    = (int*)alloc(sizeof(int) * (N_NODES + 1));
    int*    cursor = (int*)alloc(sizeof(int) * N_NODES);
    int*    rowst  = (int*)alloc(sizeof(int) * (N_NODES + 1));
    float*  dinv   = (float*)alloc(sizeof(float) * N_NODES);
    int2*   csr    = (int2*)alloc(sizeof(int2) * N_EDGES);
    int*    btot   = (int*)alloc(sizeof(int) * 64);
    int*    bpre   = (int*)alloc(sizeof(int) * 64);

    hipMemsetAsync(cnt, 0, (size_t)((char*)rowst - (char*)cnt), stream);

    const int eb = (N_EDGES + 255) / 256;
    const int gb = (N_NODES / 16 + 3) / 4;         // 782 blocks, wave-per-16-row-group
    const int pb = (N_NODES + 63) / 64;            // 782
    const int sb = (N_NODES + 1023) / 1024;        // 49

    WSrc wsrc;
    wsrc.p[0] = enc_W; wsrc.p[1] = phi_w2; wsrc.p[2] = rho_w1; wsrc.p[3] = rho_w2;
    for (int l = 0; l < 4; ++l) wsrc.p[4 + l] = conv_W + (size_t)l * 9216;
    wsrc.p[8] = head_w1;
    k_prep<<<(12288 + 8 * 9216 + 255) / 256, 256, 0, stream>>>(wsrc, wbf);

    k_count<<<eb, 256, 0, stream>>>(dst, cnt);
    k_scanA<<<sb, 1024, 0, stream>>>(cnt, rowst, btot, dinv, N_NODES);
    k_scanB<<<1, 64, 0, stream>>>(btot, bpre, rowst, N_NODES, sb);
    k_scanC<<<sb, 1024, 0, stream>>>(rowst, bpre, N_NODES);
    k_fill<<<eb, 256, 0, stream>>>(src, dst, dinv, rowst, cursor, csr);

    const ushort* w_enc  = wbf;
    const ushort* w_phi2 = wbf + 12288;
    const ushort* w_rho1 = wbf + 12288 + 9216;
    const ushort* w_rho2 = wbf + 12288 + 2 * 9216;
    const ushort* w_head = wbf + 12288 + 7 * 9216;

    // encoder: h = LN(x @ enc_W + enc_b)
    k_gemm<IN_DIM, float, 2><<<gb, 256, 0, stream>>>(x, w_enc, enc_b, in_g, in_b,
                                                     nullptr, nullptr, h);

    // fused PE chain: h += PE, hb = bf16(h)
    k_pe<<<pb, 256, 0, stream>>>(eigvecs, eigvals, pe_eps, phi_w1, w_phi2, w_rho1, w_rho2,
                                 rho_b1, rho_b2, h, hb);

    // GCN layers
    for (int l = 0; l < L_LAYERS; ++l) {
        k_gemm<96, ushort, 0><<<gb, 256, 0, stream>>>(hb, wbf + 12288 + (size_t)(3 + l) * 9216,
                                                      nullptr, nullptr, nullptr, nullptr, nullptr, bufA);
        k_agg<<<2048, 256, 0, stream>>>((const unsigned int*)bufA, rowst, csr, dinv,
                                        conv_b + (size_t)l * 96, norm_g + (size_t)l * 96,
                                        norm_b + (size_t)l * 96, h, hb);
    }

    // fused head: out = LN(gelu(h@w1+b1)) @ w2 + b2
    k_gemm<96, ushort, 5><<<gb, 256, 0, stream>>>(hb, w_head, head_b1, head_g, head_b,
                                                  head_w2, head_b2, out);
}